// Round 18
// baseline (944.160 us; speedup 1.0000x reference)
//
#include <hip/hip_runtime.h>
#include <hip/hip_bf16.h>
#include <hip/hip_fp16.h>

#define N_NODES 100000
#define N_EDGES 1600000
#define HEADS 4
#define CHN 32
#define HID 128
#define LAYERS 4
#define IN_F 8
#define ED_F 6
#define OUT_F 256
#define NEG_SLOPE 0.2f

#define NT_GEMM ((N_NODES + 63) / 64)   // 1563 row-tiles
#define GRID_GEMM 512                    // 2 blocks/CU, persistent

typedef _Float16 f16x8 __attribute__((ext_vector_type(8)));
typedef _Float16 f16x4 __attribute__((ext_vector_type(4)));
typedef _Float16 h2 __attribute__((ext_vector_type(2)));
typedef float f32x4 __attribute__((ext_vector_type(4)));

#if defined(__has_builtin)
#if __has_builtin(__builtin_amdgcn_fdot2)
#define HAVE_FDOT2 1
#endif
#endif

__device__ __forceinline__ float elu_f(float x) {
    return x > 0.f ? x : expm1f(x);
}

__device__ __forceinline__ h2 bith2(float f) {
    union { float f; h2 h; } u; u.f = f; return u.h;
}

__device__ __forceinline__ float fdot2f(h2 a, h2 b, float c) {
#ifdef HAVE_FDOT2
    return __builtin_amdgcn_fdot2(a, b, c, false);
#else
    return fmaf((float)a[1], (float)b[1], fmaf((float)a[0], (float)b[0], c));
#endif
}

__device__ __forceinline__ float dot6(h2 e01, h2 e23, h2 e45, const h2* w) {
#ifdef HAVE_FDOT2
    return __builtin_amdgcn_fdot2(e45, w[2],
           __builtin_amdgcn_fdot2(e23, w[1],
           __builtin_amdgcn_fdot2(e01, w[0], 0.f, false), false), false);
#else
    float s = (float)e01[0] * (float)w[0][0];
    s = fmaf((float)e01[1], (float)w[0][1], s);
    s = fmaf((float)e23[0], (float)w[1][0], s);
    s = fmaf((float)e23[1], (float)w[1][1], s);
    s = fmaf((float)e45[0], (float)w[2][0], s);
    s = fmaf((float)e45[1], (float)w[2][1], s);
    return s;
#endif
}

// pack two f32 -> h2 in one inst where available
__device__ __forceinline__ h2 pk16(float a, float b) {
#if defined(__has_builtin)
#if __has_builtin(__builtin_amdgcn_cvt_pkrtz)
    auto r = __builtin_amdgcn_cvt_pkrtz(a, b);
    union { decltype(r) s; h2 d; } u; u.s = r; return u.d;
#else
    h2 x; x[0] = (_Float16)a; x[1] = (_Float16)b; return x;
#endif
#else
    h2 x; x[0] = (_Float16)a; x[1] = (_Float16)b; return x;
#endif
}

// ---------------- CSR build ----------------

__global__ void hist_kernel(const int* __restrict__ dst, int* __restrict__ fill) {
    int e = blockIdx.x * blockDim.x + threadIdx.x;
    if (e < N_EDGES) atomicAdd(&fill[dst[e]], 1);
}

__global__ void scan1_kernel(const int* __restrict__ cnt, int* __restrict__ bsum) {
    __shared__ int sd[256];
    int t = threadIdx.x;
    int base = blockIdx.x * 1024 + t * 4;
    int s = 0;
#pragma unroll
    for (int j = 0; j < 4; ++j) {
        int i = base + j;
        if (i < N_NODES) s += cnt[i];
    }
    sd[t] = s;
    for (int off = 128; off > 0; off >>= 1) {
        __syncthreads();
        if (t < off) sd[t] += sd[t + off];
    }
    if (t == 0) bsum[blockIdx.x] = sd[0];
}

__global__ void scan2_kernel(int* __restrict__ bsum, int* __restrict__ rowptr, int nb) {
    __shared__ int sd[256];
    int t = threadIdx.x;
    int v = (t < nb) ? bsum[t] : 0;
    sd[t] = v;
    __syncthreads();
    for (int off = 1; off < 256; off <<= 1) {
        int x = (t >= off) ? sd[t - off] : 0;
        __syncthreads();
        sd[t] += x;
        __syncthreads();
    }
    if (t < nb) bsum[t] = sd[t] - v;
    if (t == 0) rowptr[N_NODES] = sd[255];
}

__global__ void scan3_kernel(const int* __restrict__ cnt, const int* __restrict__ bsum,
                             int* __restrict__ rowptr) {
    __shared__ int sd[256];
    int t = threadIdx.x;
    int base = blockIdx.x * 1024 + t * 4;
    int v[4];
#pragma unroll
    for (int j = 0; j < 4; ++j) {
        int i = base + j;
        v[j] = (i < N_NODES) ? cnt[i] : 0;
    }
    int s = v[0] + v[1] + v[2] + v[3];
    sd[t] = s;
    __syncthreads();
    for (int off = 1; off < 256; off <<= 1) {
        int xv = (t >= off) ? sd[t - off] : 0;
        __syncthreads();
        sd[t] += xv;
        __syncthreads();
    }
    int excl = sd[t] - s + bsum[blockIdx.x];
    int pre = 0;
#pragma unroll
    for (int j = 0; j < 4; ++j) {
        int i = base + j;
        if (i < N_NODES) rowptr[i] = excl + pre;
        pre += v[j];
    }
}

// csr BYTE offsets: x = src*512 (xlr f16 row of 256), y = eid*16 (padded f16 eattr row)
__global__ void fill_kernel(const int* __restrict__ src, const int* __restrict__ dst,
                            const int* __restrict__ rowptr, int* __restrict__ fill,
                            int2* __restrict__ csr) {
    int e = blockIdx.x * blockDim.x + threadIdx.x;
    if (e >= N_EDGES) return;
    int d = dst[e];
    int p = rowptr[d] + atomicAdd(&fill[d], 1);
    csr[p] = make_int2(src[e] * 512, e * 16);
}

// eattr -> padded f16 [E][8]
__global__ void ecvt_kernel(const float* __restrict__ eattr, __half* __restrict__ ea16) {
    int gid = blockIdx.x * blockDim.x + threadIdx.x;
    if (gid >= N_EDGES * 8) return;
    int e = gid >> 3, d = gid & 7;
    float v = (d < ED_F) ? eattr[e * ED_F + d] : 0.f;
    ea16[gid] = __float2half_rn(v);
}

// loop_attr = mean of incoming edge_attr per node, padded f16 [N][8]; gathers from ea16
__global__ void lattr_kernel(const int* __restrict__ rowptr, const int2* __restrict__ csr,
                             const __half* __restrict__ ea16, __half* __restrict__ lat16) {
    int gid = blockIdx.x * blockDim.x + threadIdx.x;
    if (gid >= N_NODES * 8) return;
    int n = gid >> 3;
    int d = gid & 7;
    float s = 0.f;
    if (d < ED_F) {
        int rp0 = rowptr[n], rp1 = rowptr[n + 1];
        for (int p = rp0; p < rp1; ++p) {
            int eid = csr[p].y >> 4;
            s += (float)ea16[(size_t)eid * 8 + d];
        }
        int deg = rp1 - rp0;
        s /= (float)(deg > 0 ? deg : 1);
    }
    lat16[gid] = __float2half_rn(s);
}

// ---------------- weight conversion: 5 panels [256][128] f16 XOR-swizzled (B) -------

__global__ void convw_kernel(const float* __restrict__ W_l, const float* __restrict__ W_r,
                             const float* __restrict__ W_out, __half* __restrict__ wbt) {
    int gid = blockIdx.x * blockDim.x + threadIdx.x;
    if (gid >= 5 * 256 * 128) return;
    int b = gid >> 15;
    int idx = gid & 32767;
    int n = idx >> 7, k = idx & 127;
    float val;
    if (b < 4)
        val = (n < HID) ? W_l[b * HID * HID + k * HID + n]
                        : W_r[b * HID * HID + k * HID + (n - HID)];
    else
        val = W_out[k * OUT_F + n];
    int boff = n * 256 + ((k * 2) ^ ((n & 7) << 4));
    *(__half*)((char*)wbt + (size_t)b * 65536 + boff) = __float2half_rn(val);
}

// ---------------- input MLP: h16 = ELU(x @ W_in + b_in), stored f16 ----------------

__global__ void in_kernel(const float* __restrict__ x, const float* __restrict__ Wi,
                          const float* __restrict__ bi, __half* __restrict__ h16) {
    int gid = blockIdx.x * blockDim.x + threadIdx.x;
    if (gid >= N_NODES * HID) return;
    int n = gid >> 7, j = gid & 127;
    float acc = bi[j];
#pragma unroll
    for (int k = 0; k < IN_F; ++k) acc = fmaf(x[n * IN_F + k], Wi[k * HID + j], acc);
    h16[gid] = __float2half_rn(elu_f(acc));
}

// ---------------- persistent MFMA GEMM, barrier-free tile loop ----------------
// B panel (64KB, pre-swizzled) staged in LDS once. A fragments loaded DIRECTLY
// global -> registers (each A row read exactly once per tile; lanes with equal lc
// across lr merge into 64B requests). No __syncthreads in the tile loop -> the
// compiler software-pipelines tile t+1 loads under tile t MFMA/stores.
// MODE 0: cols 0..127 -> xlr16 f16 (+bl); cols 128..255 -> xlr16 (+br)
// MODE 1: all 256 cols -> outp f32 (+b_out)

template <int MODE>
__global__ __launch_bounds__(256, 2) void gemm_kernel(
    const __half* __restrict__ A16, const __half* __restrict__ Bt,
    const float* __restrict__ bias0, const float* __restrict__ bias1,
    __half* __restrict__ xlr16, float* __restrict__ outp) {
    __shared__ __align__(16) unsigned char smem[65536];
    int t = threadIdx.x;

    // stage B once: pre-swizzled global -> linear LDS copy (65536 B)
#pragma unroll
    for (int it = 0; it < 16; ++it) {
        int off = (it * 256 + t) * 16;
        *(float4*)(smem + off) = *(const float4*)((const char*)Bt + off);
    }
    __syncthreads();   // B ready; LDS is read-only hereafter

    int wave = t >> 6;
    int lane = t & 63;
    int lc = lane & 15, lr = lane >> 4;
    int cbase = wave * 64;

    // hoist bias (per-thread cols fixed across tiles)
    float bcol[4];
#pragma unroll
    for (int ct = 0; ct < 4; ++ct) {
        int col = cbase + ct * 16 + lc;
        if (MODE == 0) bcol[ct] = (col < HID) ? bias0[col] : bias1[col - HID];
        else bcol[ct] = bias0[col];
    }

    for (int tile = blockIdx.x; tile < NT_GEMM; tile += GRID_GEMM) {
        int row0 = tile * 64;
        const char* abase = (const char*)A16 + (size_t)row0 * 256;

        f32x4 acc[4][4];
#pragma unroll
        for (int i = 0; i < 4; ++i)
#pragma unroll
            for (int j = 0; j < 4; ++j) acc[i][j] = (f32x4){0.f, 0.f, 0.f, 0.f};

#pragma unroll
        for (int kk = 0; kk < 4; ++kk) {
            int kb = kk * 64 + lr * 16;
            f16x8 av[4], bv[4];
#pragma unroll
            for (int rt = 0; rt < 4; ++rt)
                av[rt] = *(const f16x8*)(abase + (size_t)(rt * 16 + lc) * 256 + kb);
#pragma unroll
            for (int ct = 0; ct < 4; ++ct) {
                int c = cbase + ct * 16 + lc;
                bv[ct] = *(const f16x8*)(smem + c * 256 + (kb ^ ((c & 7) << 4)));
            }
#pragma unroll
            for (int rt = 0; rt < 4; ++rt)
#pragma unroll
                for (int ct = 0; ct < 4; ++ct)
                    acc[rt][ct] = __builtin_amdgcn_mfma_f32_16x16x32_f16(av[rt], bv[ct],
                                                                         acc[rt][ct], 0, 0, 0);
        }

        // epilogue (C/D: col = lane&15, row = (lane>>4)*4 + q); no barrier needed
#pragma unroll
        for (int ct = 0; ct < 4; ++ct) {
            int col = cbase + ct * 16 + lc;
#pragma unroll
            for (int rt = 0; rt < 4; ++rt) {
#pragma unroll
                for (int q = 0; q < 4; ++q) {
                    int node = row0 + rt * 16 + lr * 4 + q;
                    if (node < N_NODES) {
                        float val = acc[rt][ct][q] + bcol[ct];
                        if (MODE == 0)
                            xlr16[(size_t)node * 256 + col] = __float2half_rn(val);
                        else
                            outp[(size_t)node * OUT_F + col] = val;
                    }
                }
            }
        }
    }
}

// ---------------- fused edge kernel: 2 edges/wave, 4 ch/lane (R17, FROZEN) ----------
// 154 us @ 93% VALUBusy / 32 VGPR / 82% occ. Two optimization attempts (R14, R17)
// were neutral-to-negative -> do not touch.

struct Slot {
    float4 er;   // 8 f16: eattr row (padded)
    float2 xv;   // 4 f16: xl[src] channels c0..c0+3
};

__device__ __forceinline__ void slot_issue(Slot& s, int i, int total, int rp0,
                                           const int2* __restrict__ csr,
                                           const char* eab, const char* lat16v,
                                           const char* xlb, int vbytes) {
    i = min(i, total - 1);
    const char* eb;
    const char* xb;
    if (i == 0) {
        eb = lat16v;
        xb = xlb + (size_t)vbytes;
    } else {
        int2 se = csr[rp0 + i - 1];
        eb = eab + (size_t)se.y;
        xb = xlb + (size_t)se.x;
    }
    s.er = *(const float4*)eb;
    s.xv = *(const float2*)xb;
}

__device__ __forceinline__ void slot_consume(const Slot& sl, int i, int total,
                                             const h2 we_h2[4][3], const h2* att2,
                                             const h2* xr2, float& denom, float* acc) {
    h2 e01 = bith2(sl.er.x), e23 = bith2(sl.er.y), e45 = bith2(sl.er.z);
    h2 xl0 = bith2(sl.xv.x), xl1 = bith2(sl.xv.y);
    float ea0 = dot6(e01, e23, e45, we_h2[0]);
    float ea1 = dot6(e01, e23, e45, we_h2[1]);
    float ea2 = dot6(e01, e23, e45, we_h2[2]);
    float ea3 = dot6(e01, e23, e45, we_h2[3]);
    h2 sp0 = xl0 + xr2[0] + pk16(ea0, ea1);
    h2 sp1 = xl1 + xr2[1] + pk16(ea2, ea3);
    const h2 kns = {(_Float16)NEG_SLOPE, (_Float16)NEG_SLOPE};
    h2 l0 = __builtin_elementwise_max(sp0, sp0 * kns);   // leaky = max(s, 0.2s)
    h2 l1 = __builtin_elementwise_max(sp1, sp1 * kns);
    float t = fdot2f(l1, att2[1], fdot2f(l0, att2[0], 0.f));
    // head reduce: 8 lanes x 4 ch = 32 channels (within half-wave)
    t += __shfl_xor(t, 1);
    t += __shfl_xor(t, 2);
    t += __shfl_xor(t, 4);
    float ex = exp2f(t);          // att pre-scaled by log2(e): exp(score) == 2^t
    ex = (i < total) ? ex : 0.f;
    denom += ex;
    acc[0] = fmaf((float)xl0[0], ex, acc[0]);
    acc[1] = fmaf((float)xl0[1], ex, acc[1]);
    acc[2] = fmaf((float)xl1[0], ex, acc[2]);
    acc[3] = fmaf((float)xl1[1], ex, acc[3]);
}

// NOTE: 2nd launch_bounds arg = VGPR budget 256/n on this toolchain.
// (64,8) -> 32 VGPR. Spills show as WRITE_SIZE blowup (R11: +2GB, R14: +50MB). Tripwire.
__global__ __launch_bounds__(64, 8) void edge_kernel(
    const __half* __restrict__ xlr16,   // [N][256]: cols 0..127 = xl, 128..255 = xr
    __half* __restrict__ h16,           // in-place residual read + output write
    const int* __restrict__ rowptr, const int2* __restrict__ csr,
    const __half* __restrict__ ea16, const __half* __restrict__ lat16,
    const float* __restrict__ We, const float* __restrict__ att,
    const float* __restrict__ bias_l, const float* __restrict__ lnw,
    const float* __restrict__ lnb) {
    int v = blockIdx.x;
    int lane = threadIdx.x;
    int half = lane >> 5;
    int hl = lane & 31;
    int c0 = hl * 4;

    h2 we_h2[4][3];
#pragma unroll
    for (int c = 0; c < 4; ++c)
#pragma unroll
        for (int d = 0; d < 3; ++d) {
            h2 w;
            w[0] = (_Float16)We[(2 * d) * HID + c0 + c];
            w[1] = (_Float16)We[(2 * d + 1) * HID + c0 + c];
            we_h2[c][d] = w;
        }
    const float L2E = 1.44269504f;
    h2 att2[2];
    {
        float4 a = *(const float4*)(att + c0);
        h2 t0, t1;
        t0[0] = (_Float16)(a.x * L2E); t0[1] = (_Float16)(a.y * L2E);
        t1[0] = (_Float16)(a.z * L2E); t1[1] = (_Float16)(a.w * L2E);
        att2[0] = t0; att2[1] = t1;
    }
    h2 xr2[2];
    {
        float2 xraw = *(const float2*)(xlr16 + (size_t)v * 256 + 128 + c0);
        xr2[0] = bith2(xraw.x); xr2[1] = bith2(xraw.y);
    }

    int rp0 = rowptr[v], rp1 = rowptr[v + 1];
    int total = (rp1 - rp0) + 1;
    int R = (total + 1) >> 1;

    const char* xlb = (const char*)xlr16 + (size_t)c0 * 2;
    const char* eab = (const char*)ea16;
    const char* lat16v = (const char*)lat16 + (size_t)v * 16;
    int vbytes = v * 512;

    float denom = 0.f;
    float acc[4] = {0.f, 0.f, 0.f, 0.f};

    Slot sA, sB;
    slot_issue(sA, half, total, rp0, csr, eab, lat16v, xlb, vbytes);
    if (R > 1) slot_issue(sB, 2 + half, total, rp0, csr, eab, lat16v, xlb, vbytes);
    int r = 0;
    for (; r + 2 <= R; r += 2) {
        slot_consume(sA, 2 * r + half, total, we_h2, att2, xr2, denom, acc);
        if (r + 2 < R) slot_issue(sA, 2 * (r + 2) + half, total, rp0, csr, eab, lat16v, xlb, vbytes);
        slot_consume(sB, 2 * (r + 1) + half, total, we_h2, att2, xr2, denom, acc);
        if (r + 3 < R) slot_issue(sB, 2 * (r + 3) + half, total, rp0, csr, eab, lat16v, xlb, vbytes);
    }
    if (r < R) slot_consume(sA, 2 * r + half, total, we_h2, att2, xr2, denom, acc);

    denom += __shfl_xor(denom, 32);
#pragma unroll
    for (int c = 0; c < 4; ++c) acc[c] += __shfl_xor(acc[c], 32);

    float rd = 1.f / denom;

    // ---- epilogue: bias + residual(f16) + LayerNorm + ELU -> h16
    float2 rb = *(const float2*)(h16 + (size_t)v * HID + c0);
    h2 r01 = bith2(rb.x), r23 = bith2(rb.y);
    float4 bv4 = *(const float4*)(bias_l + c0);
    float y[4];
    y[0] = acc[0] * rd + bv4.x + (float)r01[0];
    y[1] = acc[1] * rd + bv4.y + (float)r01[1];
    y[2] = acc[2] * rd + bv4.z + (float)r23[0];
    y[3] = acc[3] * rd + bv4.w + (float)r23[1];
    float s = y[0] + y[1] + y[2] + y[3];
    float sq = fmaf(y[0], y[0], fmaf(y[1], y[1], fmaf(y[2], y[2], y[3] * y[3])));
#pragma unroll
    for (int off = 1; off < 32; off <<= 1) {
        s += __shfl_xor(s, off);
        sq += __shfl_xor(sq, off);
    }
    float mu = s * (1.f / HID);
    float var = sq * (1.f / HID) - mu * mu;
    float rstd = rsqrtf(var + 1e-5f);
    float4 wv4 = *(const float4*)(lnw + c0);
    float4 lb4 = *(const float4*)(lnb + c0);
    if (half == 0) {
        f16x4 o;
        o[0] = (_Float16)elu_f((y[0] - mu) * rstd * wv4.x + lb4.x);
        o[1] = (_Float16)elu_f((y[1] - mu) * rstd * wv4.y + lb4.y);
        o[2] = (_Float16)elu_f((y[2] - mu) * rstd * wv4.z + lb4.z);
        o[3] = (_Float16)elu_f((y[3] - mu) * rstd * wv4.w + lb4.w);
        *(f16x4*)(h16 + (size_t)v * HID + c0) = o;
    }
}

// ---------------- launch ----------------

extern "C" void kernel_launch(void* const* d_in, const int* in_sizes, int n_in,
                              void* d_out, int out_size, void* d_ws, size_t ws_size,
                              hipStream_t stream) {
    const float* x     = (const float*)d_in[0];
    const int*   ei    = (const int*)d_in[1];
    const float* eattr = (const float*)d_in[2];
    const float* W_in  = (const float*)d_in[3];
    const float* b_in  = (const float*)d_in[4];
    const float* W_l   = (const float*)d_in[5];
    const float* b_l   = (const float*)d_in[6];
    const float* W_r   = (const float*)d_in[7];
    const float* b_r   = (const float*)d_in[8];
    const float* W_e   = (const float*)d_in[9];
    const float* att   = (const float*)d_in[10];
    const float* bias  = (const float*)d_in[11];
    const float* lnw   = (const float*)d_in[12];
    const float* lnb   = (const float*)d_in[13];
    const float* W_out = (const float*)d_in[14];
    const float* b_out = (const float*)d_in[15];
    float* out = (float*)d_out;

    // workspace: h16 | lat16 | rowptr | fill | csr | bsum | wbt
    __half* h16   = (__half*)d_ws;
    __half* lat16 = h16 + (size_t)N_NODES * HID;                 // N*8 f16
    int* rowptr   = (int*)(lat16 + (size_t)N_NODES * 8);
    int* fill     = rowptr + (N_NODES + 4);
    int2* csr     = (int2*)(fill + N_NODES);
    int* bsum     = (int*)(csr + N_EDGES);
    __half* wbt   = (__half*)(bsum + 256);   // 5 x 65536 B f16 GEMM panels

    // d_out (102.4 MB): xlr16 [N][256] f16 (51.2) | ea16 [E][8] f16 (25.6)
    __half* xlr16 = (__half*)out;
    __half* ea16  = xlr16 + (size_t)N_NODES * 256;

    const int* srcv = ei;
    const int* dstv = ei + N_EDGES;

    hipMemsetAsync(fill, 0, N_NODES * sizeof(int), stream);
    hist_kernel<<<(N_EDGES + 255) / 256, 256, 0, stream>>>(dstv, fill);
    int nb = (N_NODES + 1023) / 1024;
    scan1_kernel<<<nb, 256, 0, stream>>>(fill, bsum);
    scan2_kernel<<<1, 256, 0, stream>>>(bsum, rowptr, nb);
    scan3_kernel<<<nb, 256, 0, stream>>>(fill, bsum, rowptr);
    hipMemsetAsync(fill, 0, N_NODES * sizeof(int), stream);
    fill_kernel<<<(N_EDGES + 255) / 256, 256, 0, stream>>>(srcv, dstv, rowptr, fill, csr);
    ecvt_kernel<<<(N_EDGES * 8 + 255) / 256, 256, 0, stream>>>(eattr, ea16);
    lattr_kernel<<<(N_NODES * 8 + 255) / 256, 256, 0, stream>>>(rowptr, csr, ea16, lat16);

    convw_kernel<<<(5 * 256 * 128 + 255) / 256, 256, 0, stream>>>(W_l, W_r, W_out, wbt);
    in_kernel<<<(N_NODES * HID) / 256, 256, 0, stream>>>(x, W_in, b_in, h16);

    for (int l = 0; l < LAYERS; ++l) {
        gemm_kernel<0><<<GRID_GEMM, 256, 0, stream>>>(
            h16, wbt + (size_t)l * 32768, b_l + (size_t)l * HID, b_r + (size_t)l * HID,
            xlr16, nullptr);
        edge_kernel<<<N_NODES, 64, 0, stream>>>(
            xlr16, h16, rowptr, csr, ea16, lat16,
            W_e + (size_t)l * ED_F * HID, att + (size_t)l * HEADS * CHN,
            bias + (size_t)l * HID, lnw + (size_t)l * HID, lnb + (size_t)l * HID);
    }

    gemm_kernel<1><<<GRID_GEMM, 256, 0, stream>>>(
        h16, wbt + (size_t)4 * 32768, b_out, nullptr, nullptr, out);
}

// Round 19
// 926.053 us; speedup vs baseline: 1.0196x; 1.0196x over previous
//
#include <hip/hip_runtime.h>
#include <hip/hip_bf16.h>
#include <hip/hip_fp16.h>

#define N_NODES 100000
#define N_EDGES 1600000
#define HEADS 4
#define CHN 32
#define HID 128
#define LAYERS 4
#define IN_F 8
#define ED_F 6
#define OUT_F 256
#define NEG_SLOPE 0.2f

#define NT_GEMM ((N_NODES + 63) / 64)   // 1563 row-tiles
#define GRID_GEMM 512                    // 2 blocks/CU, persistent

typedef _Float16 f16x8 __attribute__((ext_vector_type(8)));
typedef _Float16 f16x4 __attribute__((ext_vector_type(4)));
typedef _Float16 h2 __attribute__((ext_vector_type(2)));
typedef float f32x4 __attribute__((ext_vector_type(4)));
typedef float f32x2 __attribute__((ext_vector_type(2)));

#if defined(__has_builtin)
#if __has_builtin(__builtin_amdgcn_fdot2)
#define HAVE_FDOT2 1
#endif
#endif

__device__ __forceinline__ float elu_f(float x) {
    return x > 0.f ? x : expm1f(x);
}

__device__ __forceinline__ h2 bith2(float f) {
    union { float f; h2 h; } u; u.f = f; return u.h;
}

__device__ __forceinline__ float fdot2f(h2 a, h2 b, float c) {
#ifdef HAVE_FDOT2
    return __builtin_amdgcn_fdot2(a, b, c, false);
#else
    return fmaf((float)a[1], (float)b[1], fmaf((float)a[0], (float)b[0], c));
#endif
}

__device__ __forceinline__ float dot6(h2 e01, h2 e23, h2 e45, const h2* w) {
#ifdef HAVE_FDOT2
    return __builtin_amdgcn_fdot2(e45, w[2],
           __builtin_amdgcn_fdot2(e23, w[1],
           __builtin_amdgcn_fdot2(e01, w[0], 0.f, false), false), false);
#else
    float s = (float)e01[0] * (float)w[0][0];
    s = fmaf((float)e01[1], (float)w[0][1], s);
    s = fmaf((float)e23[0], (float)w[1][0], s);
    s = fmaf((float)e23[1], (float)w[1][1], s);
    s = fmaf((float)e45[0], (float)w[2][0], s);
    s = fmaf((float)e45[1], (float)w[2][1], s);
    return s;
#endif
}

// pack two f32 -> h2 in one inst where available
__device__ __forceinline__ h2 pk16(float a, float b) {
#if defined(__has_builtin)
#if __has_builtin(__builtin_amdgcn_cvt_pkrtz)
    auto r = __builtin_amdgcn_cvt_pkrtz(a, b);
    union { decltype(r) s; h2 d; } u; u.s = r; return u.d;
#else
    h2 x; x[0] = (_Float16)a; x[1] = (_Float16)b; return x;
#endif
#else
    h2 x; x[0] = (_Float16)a; x[1] = (_Float16)b; return x;
#endif
}

// ---------------- CSR build ----------------

__global__ void hist_kernel(const int* __restrict__ dst, int* __restrict__ fill) {
    int e = blockIdx.x * blockDim.x + threadIdx.x;
    if (e < N_EDGES) atomicAdd(&fill[dst[e]], 1);
}

__global__ void scan1_kernel(const int* __restrict__ cnt, int* __restrict__ bsum) {
    __shared__ int sd[256];
    int t = threadIdx.x;
    int base = blockIdx.x * 1024 + t * 4;
    int s = 0;
#pragma unroll
    for (int j = 0; j < 4; ++j) {
        int i = base + j;
        if (i < N_NODES) s += cnt[i];
    }
    sd[t] = s;
    for (int off = 128; off > 0; off >>= 1) {
        __syncthreads();
        if (t < off) sd[t] += sd[t + off];
    }
    if (t == 0) bsum[blockIdx.x] = sd[0];
}

__global__ void scan2_kernel(int* __restrict__ bsum, int* __restrict__ rowptr, int nb) {
    __shared__ int sd[256];
    int t = threadIdx.x;
    int v = (t < nb) ? bsum[t] : 0;
    sd[t] = v;
    __syncthreads();
    for (int off = 1; off < 256; off <<= 1) {
        int x = (t >= off) ? sd[t - off] : 0;
        __syncthreads();
        sd[t] += x;
        __syncthreads();
    }
    if (t < nb) bsum[t] = sd[t] - v;
    if (t == 0) rowptr[N_NODES] = sd[255];
}

__global__ void scan3_kernel(const int* __restrict__ cnt, const int* __restrict__ bsum,
                             int* __restrict__ rowptr) {
    __shared__ int sd[256];
    int t = threadIdx.x;
    int base = blockIdx.x * 1024 + t * 4;
    int v[4];
#pragma unroll
    for (int j = 0; j < 4; ++j) {
        int i = base + j;
        v[j] = (i < N_NODES) ? cnt[i] : 0;
    }
    int s = v[0] + v[1] + v[2] + v[3];
    sd[t] = s;
    __syncthreads();
    for (int off = 1; off < 256; off <<= 1) {
        int xv = (t >= off) ? sd[t - off] : 0;
        __syncthreads();
        sd[t] += xv;
        __syncthreads();
    }
    int excl = sd[t] - s + bsum[blockIdx.x];
    int pre = 0;
#pragma unroll
    for (int j = 0; j < 4; ++j) {
        int i = base + j;
        if (i < N_NODES) rowptr[i] = excl + pre;
        pre += v[j];
    }
}

// csr BYTE offsets: x = src*512 (xlr f16 row of 256), y = eid*16 (padded f16 eattr row)
__global__ void fill_kernel(const int* __restrict__ src, const int* __restrict__ dst,
                            const int* __restrict__ rowptr, int* __restrict__ fill,
                            int2* __restrict__ csr) {
    int e = blockIdx.x * blockDim.x + threadIdx.x;
    if (e >= N_EDGES) return;
    int d = dst[e];
    int p = rowptr[d] + atomicAdd(&fill[d], 1);
    csr[p] = make_int2(src[e] * 512, e * 16);
}

// eattr -> padded f16 [E][8]
__global__ void ecvt_kernel(const float* __restrict__ eattr, __half* __restrict__ ea16) {
    int gid = blockIdx.x * blockDim.x + threadIdx.x;
    if (gid >= N_EDGES * 8) return;
    int e = gid >> 3, d = gid & 7;
    float v = (d < ED_F) ? eattr[e * ED_F + d] : 0.f;
    ea16[gid] = __float2half_rn(v);
}

// loop_attr = mean of incoming edge_attr per node, padded f16 [N][8]; gathers from ea16
__global__ void lattr_kernel(const int* __restrict__ rowptr, const int2* __restrict__ csr,
                             const __half* __restrict__ ea16, __half* __restrict__ lat16) {
    int gid = blockIdx.x * blockDim.x + threadIdx.x;
    if (gid >= N_NODES * 8) return;
    int n = gid >> 3;
    int d = gid & 7;
    float s = 0.f;
    if (d < ED_F) {
        int rp0 = rowptr[n], rp1 = rowptr[n + 1];
        for (int p = rp0; p < rp1; ++p) {
            int eid = csr[p].y >> 4;
            s += (float)ea16[(size_t)eid * 8 + d];
        }
        int deg = rp1 - rp0;
        s /= (float)(deg > 0 ? deg : 1);
    }
    lat16[gid] = __float2half_rn(s);
}

// ---------------- weight conversion: 5 panels [256][128] f16 XOR-swizzled (B) -------

__global__ void convw_kernel(const float* __restrict__ W_l, const float* __restrict__ W_r,
                             const float* __restrict__ W_out, __half* __restrict__ wbt) {
    int gid = blockIdx.x * blockDim.x + threadIdx.x;
    if (gid >= 5 * 256 * 128) return;
    int b = gid >> 15;
    int idx = gid & 32767;
    int n = idx >> 7, k = idx & 127;
    float val;
    if (b < 4)
        val = (n < HID) ? W_l[b * HID * HID + k * HID + n]
                        : W_r[b * HID * HID + k * HID + (n - HID)];
    else
        val = W_out[k * OUT_F + n];
    int boff = n * 256 + ((k * 2) ^ ((n & 7) << 4));
    *(__half*)((char*)wbt + (size_t)b * 65536 + boff) = __float2half_rn(val);
}

// ---------------- input MLP: h16 = ELU(x @ W_in + b_in), stored f16 ----------------

__global__ void in_kernel(const float* __restrict__ x, const float* __restrict__ Wi,
                          const float* __restrict__ bi, __half* __restrict__ h16) {
    int gid = blockIdx.x * blockDim.x + threadIdx.x;
    if (gid >= N_NODES * HID) return;
    int n = gid >> 7, j = gid & 127;
    float acc = bi[j];
#pragma unroll
    for (int k = 0; k < IN_F; ++k) acc = fmaf(x[n * IN_F + k], Wi[k * HID + j], acc);
    h16[gid] = __float2half_rn(elu_f(acc));
}

// ---------------- persistent MFMA GEMM, swapped operands -> packed stores ----------
// D = W_frag x h_frag (operand swap transposes output): lane holds 4 CONSECUTIVE
// output channels (row=lr*4+q) of ONE node (col=lc) -> f16x4 8B stores (MODE 0),
// f32x4 16B stores (MODE 1). A/B load patterns identical to before (fragment
// layouts are symmetric). B panel in LDS once; h fragments direct global->reg.

template <int MODE>
__global__ __launch_bounds__(256, 2) void gemm_kernel(
    const __half* __restrict__ A16, const __half* __restrict__ Bt,
    const float* __restrict__ bias0, const float* __restrict__ bias1,
    __half* __restrict__ xlr16, float* __restrict__ outp) {
    __shared__ __align__(16) unsigned char smem[65536];
    int t = threadIdx.x;

    // stage B once: pre-swizzled global -> linear LDS copy (65536 B)
#pragma unroll
    for (int it = 0; it < 16; ++it) {
        int off = (it * 256 + t) * 16;
        *(float4*)(smem + off) = *(const float4*)((const char*)Bt + off);
    }
    __syncthreads();   // B ready; LDS is read-only hereafter

    int wave = t >> 6;
    int lane = t & 63;
    int lc = lane & 15, lr = lane >> 4;
    int cbase = wave * 64;

    // hoist bias: channel = cbase + wt*16 + lr*4 + q
    f32x4 bch[4];
#pragma unroll
    for (int wt = 0; wt < 4; ++wt) {
#pragma unroll
        for (int q = 0; q < 4; ++q) {
            int ch = cbase + wt * 16 + lr * 4 + q;
            float b;
            if (MODE == 0) b = (ch < HID) ? bias0[ch] : bias1[ch - HID];
            else b = bias0[ch];
            bch[wt][q] = b;
        }
    }

    for (int tile = blockIdx.x; tile < NT_GEMM; tile += GRID_GEMM) {
        int row0 = tile * 64;
        const char* abase = (const char*)A16 + (size_t)row0 * 256;

        // acc[wt][nt]: M = channel subtile wt, N = node subtile nt
        f32x4 acc[4][4];
#pragma unroll
        for (int i = 0; i < 4; ++i)
#pragma unroll
            for (int j = 0; j < 4; ++j) acc[i][j] = (f32x4){0.f, 0.f, 0.f, 0.f};

#pragma unroll
        for (int kk = 0; kk < 4; ++kk) {
            int kb = kk * 64 + lr * 16;
            f16x8 hv[4], wv[4];
#pragma unroll
            for (int nt = 0; nt < 4; ++nt)
                hv[nt] = *(const f16x8*)(abase + (size_t)(nt * 16 + lc) * 256 + kb);
#pragma unroll
            for (int wt = 0; wt < 4; ++wt) {
                int c = cbase + wt * 16 + lc;
                wv[wt] = *(const f16x8*)(smem + c * 256 + (kb ^ ((c & 7) << 4)));
            }
#pragma unroll
            for (int wt = 0; wt < 4; ++wt)
#pragma unroll
                for (int nt = 0; nt < 4; ++nt)
                    acc[wt][nt] = __builtin_amdgcn_mfma_f32_16x16x32_f16(wv[wt], hv[nt],
                                                                         acc[wt][nt], 0, 0, 0);
        }

        // epilogue: lane stores 4 consecutive channels of node (nt*16+lc)
#pragma unroll
        for (int nt = 0; nt < 4; ++nt) {
            int node = row0 + nt * 16 + lc;
            if (node < N_NODES) {
#pragma unroll
                for (int wt = 0; wt < 4; ++wt) {
                    int ch0 = cbase + wt * 16 + lr * 4;
                    if (MODE == 0) {
                        f16x4 o;
                        o[0] = (_Float16)(acc[wt][nt][0] + bch[wt][0]);
                        o[1] = (_Float16)(acc[wt][nt][1] + bch[wt][1]);
                        o[2] = (_Float16)(acc[wt][nt][2] + bch[wt][2]);
                        o[3] = (_Float16)(acc[wt][nt][3] + bch[wt][3]);
                        *(f16x4*)(xlr16 + (size_t)node * 256 + ch0) = o;
                    } else {
                        f32x4 o = acc[wt][nt] + bch[wt];
                        *(f32x4*)(outp + (size_t)node * OUT_F + ch0) = o;
                    }
                }
            }
        }
    }
}

// ---------------- fused edge kernel: 2 edges/wave, 4 ch/lane (R17, FROZEN) ----------
// 154 us @ 93% VALUBusy / 32 VGPR / 82% occ. Two optimization attempts (R14, R17)
// were neutral-to-negative -> do not touch.

struct Slot {
    float4 er;   // 8 f16: eattr row (padded)
    float2 xv;   // 4 f16: xl[src] channels c0..c0+3
};

__device__ __forceinline__ void slot_issue(Slot& s, int i, int total, int rp0,
                                           const int2* __restrict__ csr,
                                           const char* eab, const char* lat16v,
                                           const char* xlb, int vbytes) {
    i = min(i, total - 1);
    const char* eb;
    const char* xb;
    if (i == 0) {
        eb = lat16v;
        xb = xlb + (size_t)vbytes;
    } else {
        int2 se = csr[rp0 + i - 1];
        eb = eab + (size_t)se.y;
        xb = xlb + (size_t)se.x;
    }
    s.er = *(const float4*)eb;
    s.xv = *(const float2*)xb;
}

__device__ __forceinline__ void slot_consume(const Slot& sl, int i, int total,
                                             const h2 we_h2[4][3], const h2* att2,
                                             const h2* xr2, float& denom, float* acc) {
    h2 e01 = bith2(sl.er.x), e23 = bith2(sl.er.y), e45 = bith2(sl.er.z);
    h2 xl0 = bith2(sl.xv.x), xl1 = bith2(sl.xv.y);
    float ea0 = dot6(e01, e23, e45, we_h2[0]);
    float ea1 = dot6(e01, e23, e45, we_h2[1]);
    float ea2 = dot6(e01, e23, e45, we_h2[2]);
    float ea3 = dot6(e01, e23, e45, we_h2[3]);
    h2 sp0 = xl0 + xr2[0] + pk16(ea0, ea1);
    h2 sp1 = xl1 + xr2[1] + pk16(ea2, ea3);
    const h2 kns = {(_Float16)NEG_SLOPE, (_Float16)NEG_SLOPE};
    h2 l0 = __builtin_elementwise_max(sp0, sp0 * kns);   // leaky = max(s, 0.2s)
    h2 l1 = __builtin_elementwise_max(sp1, sp1 * kns);
    float t = fdot2f(l1, att2[1], fdot2f(l0, att2[0], 0.f));
    // head reduce: 8 lanes x 4 ch = 32 channels (within half-wave)
    t += __shfl_xor(t, 1);
    t += __shfl_xor(t, 2);
    t += __shfl_xor(t, 4);
    float ex = exp2f(t);          // att pre-scaled by log2(e): exp(score) == 2^t
    ex = (i < total) ? ex : 0.f;
    denom += ex;
    acc[0] = fmaf((float)xl0[0], ex, acc[0]);
    acc[1] = fmaf((float)xl0[1], ex, acc[1]);
    acc[2] = fmaf((float)xl1[0], ex, acc[2]);
    acc[3] = fmaf((float)xl1[1], ex, acc[3]);
}

// NOTE: 2nd launch_bounds arg = VGPR budget 256/n on this toolchain.
// (64,8) -> 32 VGPR. Spills show as WRITE_SIZE blowup (R11: +2GB, R14: +50MB). Tripwire.
__global__ __launch_bounds__(64, 8) void edge_kernel(
    const __half* __restrict__ xlr16,   // [N][256]: cols 0..127 = xl, 128..255 = xr
    __half* __restrict__ h16,           // in-place residual read + output write
    const int* __restrict__ rowptr, const int2* __restrict__ csr,
    const __half* __restrict__ ea16, const __half* __restrict__ lat16,
    const float* __restrict__ We, const float* __restrict__ att,
    const float* __restrict__ bias_l, const float* __restrict__ lnw,
    const float* __restrict__ lnb) {
    int v = blockIdx.x;
    int lane = threadIdx.x;
    int half = lane >> 5;
    int hl = lane & 31;
    int c0 = hl * 4;

    h2 we_h2[4][3];
#pragma unroll
    for (int c = 0; c < 4; ++c)
#pragma unroll
        for (int d = 0; d < 3; ++d) {
            h2 w;
            w[0] = (_Float16)We[(2 * d) * HID + c0 + c];
            w[1] = (_Float16)We[(2 * d + 1) * HID + c0 + c];
            we_h2[c][d] = w;
        }
    const float L2E = 1.44269504f;
    h2 att2[2];
    {
        float4 a = *(const float4*)(att + c0);
        h2 t0, t1;
        t0[0] = (_Float16)(a.x * L2E); t0[1] = (_Float16)(a.y * L2E);
        t1[0] = (_Float16)(a.z * L2E); t1[1] = (_Float16)(a.w * L2E);
        att2[0] = t0; att2[1] = t1;
    }
    h2 xr2[2];
    {
        float2 xraw = *(const float2*)(xlr16 + (size_t)v * 256 + 128 + c0);
        xr2[0] = bith2(xraw.x); xr2[1] = bith2(xraw.y);
    }

    int rp0 = rowptr[v], rp1 = rowptr[v + 1];
    int total = (rp1 - rp0) + 1;
    int R = (total + 1) >> 1;

    const char* xlb = (const char*)xlr16 + (size_t)c0 * 2;
    const char* eab = (const char*)ea16;
    const char* lat16v = (const char*)lat16 + (size_t)v * 16;
    int vbytes = v * 512;

    float denom = 0.f;
    float acc[4] = {0.f, 0.f, 0.f, 0.f};

    Slot sA, sB;
    slot_issue(sA, half, total, rp0, csr, eab, lat16v, xlb, vbytes);
    if (R > 1) slot_issue(sB, 2 + half, total, rp0, csr, eab, lat16v, xlb, vbytes);
    int r = 0;
    for (; r + 2 <= R; r += 2) {
        slot_consume(sA, 2 * r + half, total, we_h2, att2, xr2, denom, acc);
        if (r + 2 < R) slot_issue(sA, 2 * (r + 2) + half, total, rp0, csr, eab, lat16v, xlb, vbytes);
        slot_consume(sB, 2 * (r + 1) + half, total, we_h2, att2, xr2, denom, acc);
        if (r + 3 < R) slot_issue(sB, 2 * (r + 3) + half, total, rp0, csr, eab, lat16v, xlb, vbytes);
    }
    if (r < R) slot_consume(sA, 2 * r + half, total, we_h2, att2, xr2, denom, acc);

    denom += __shfl_xor(denom, 32);
#pragma unroll
    for (int c = 0; c < 4; ++c) acc[c] += __shfl_xor(acc[c], 32);

    float rd = 1.f / denom;

    // ---- epilogue: bias + residual(f16) + LayerNorm + ELU -> h16
    float2 rb = *(const float2*)(h16 + (size_t)v * HID + c0);
    h2 r01 = bith2(rb.x), r23 = bith2(rb.y);
    float4 bv4 = *(const float4*)(bias_l + c0);
    float y[4];
    y[0] = acc[0] * rd + bv4.x + (float)r01[0];
    y[1] = acc[1] * rd + bv4.y + (float)r01[1];
    y[2] = acc[2] * rd + bv4.z + (float)r23[0];
    y[3] = acc[3] * rd + bv4.w + (float)r23[1];
    float s = y[0] + y[1] + y[2] + y[3];
    float sq = fmaf(y[0], y[0], fmaf(y[1], y[1], fmaf(y[2], y[2], y[3] * y[3])));
#pragma unroll
    for (int off = 1; off < 32; off <<= 1) {
        s += __shfl_xor(s, off);
        sq += __shfl_xor(sq, off);
    }
    float mu = s * (1.f / HID);
    float var = sq * (1.f / HID) - mu * mu;
    float rstd = rsqrtf(var + 1e-5f);
    float4 wv4 = *(const float4*)(lnw + c0);
    float4 lb4 = *(const float4*)(lnb + c0);
    if (half == 0) {
        f16x4 o;
        o[0] = (_Float16)elu_f((y[0] - mu) * rstd * wv4.x + lb4.x);
        o[1] = (_Float16)elu_f((y[1] - mu) * rstd * wv4.y + lb4.y);
        o[2] = (_Float16)elu_f((y[2] - mu) * rstd * wv4.z + lb4.z);
        o[3] = (_Float16)elu_f((y[3] - mu) * rstd * wv4.w + lb4.w);
        *(f16x4*)(h16 + (size_t)v * HID + c0) = o;
    }
}

// ---------------- launch ----------------

extern "C" void kernel_launch(void* const* d_in, const int* in_sizes, int n_in,
                              void* d_out, int out_size, void* d_ws, size_t ws_size,
                              hipStream_t stream) {
    const float* x     = (const float*)d_in[0];
    const int*   ei    = (const int*)d_in[1];
    const float* eattr = (const float*)d_in[2];
    const float* W_in  = (const float*)d_in[3];
    const float* b_in  = (const float*)d_in[4];
    const float* W_l   = (const float*)d_in[5];
    const float* b_l   = (const float*)d_in[6];
    const float* W_r   = (const float*)d_in[7];
    const float* b_r   = (const float*)d_in[8];
    const float* W_e   = (const float*)d_in[9];
    const float* att   = (const float*)d_in[10];
    const float* bias  = (const float*)d_in[11];
    const float* lnw   = (const float*)d_in[12];
    const float* lnb   = (const float*)d_in[13];
    const float* W_out = (const float*)d_in[14];
    const float* b_out = (const float*)d_in[15];
    float* out = (float*)d_out;

    // workspace: h16 | lat16 | rowptr | fill | csr | bsum | wbt
    __half* h16   = (__half*)d_ws;
    __half* lat16 = h16 + (size_t)N_NODES * HID;                 // N*8 f16
    int* rowptr   = (int*)(lat16 + (size_t)N_NODES * 8);
    int* fill     = rowptr + (N_NODES + 4);
    int2* csr     = (int2*)(fill + N_NODES);
    int* bsum     = (int*)(csr + N_EDGES);
    __half* wbt   = (__half*)(bsum + 256);   // 5 x 65536 B f16 GEMM panels

    // d_out (102.4 MB): xlr16 [N][256] f16 (51.2) | ea16 [E][8] f16 (25.6)
    __half* xlr16 = (__half*)out;
    __half* ea16  = xlr16 + (size_t)N_NODES * 256;

    const int* srcv = ei;
    const int* dstv = ei + N_EDGES;

    hipMemsetAsync(fill, 0, N_NODES * sizeof(int), stream);
    hist_kernel<<<(N_EDGES + 255) / 256, 256, 0, stream>>>(dstv, fill);
    int nb = (N_NODES + 1023) / 1024;
    scan1_kernel<<<nb, 256, 0, stream>>>(fill, bsum);
    scan2_kernel<<<1, 256, 0, stream>>>(bsum, rowptr, nb);
    scan3_kernel<<<nb, 256, 0, stream>>>(fill, bsum, rowptr);
    hipMemsetAsync(fill, 0, N_NODES * sizeof(int), stream);
    fill_kernel<<<(N_EDGES + 255) / 256, 256, 0, stream>>>(srcv, dstv, rowptr, fill, csr);
    ecvt_kernel<<<(N_EDGES * 8 + 255) / 256, 256, 0, stream>>>(eattr, ea16);
    lattr_kernel<<<(N_NODES * 8 + 255) / 256, 256, 0, stream>>>(rowptr, csr, ea16, lat16);

    convw_kernel<<<(5 * 256 * 128 + 255) / 256, 256, 0, stream>>>(W_l, W_r, W_out, wbt);
    in_kernel<<<(N_NODES * HID) / 256, 256, 0, stream>>>(x, W_in, b_in, h16);

    for (int l = 0; l < LAYERS; ++l) {
        gemm_kernel<0><<<GRID_GEMM, 256, 0, stream>>>(
            h16, wbt + (size_t)l * 32768, b_l + (size_t)l * HID, b_r + (size_t)l * HID,
            xlr16, nullptr);
        edge_kernel<<<N_NODES, 64, 0, stream>>>(
            xlr16, h16, rowptr, csr, ea16, lat16,
            W_e + (size_t)l * ED_F * HID, att + (size_t)l * HEADS * CHN,
            bias + (size_t)l * HID, lnw + (size_t)l * HID, lnb + (size_t)l * HID);
    }

    gemm_kernel<1><<<GRID_GEMM, 256, 0, stream>>>(
        h16, wbt + (size_t)4 * 32768, b_out, nullptr, nullptr, out);
}